// Round 5
// baseline (256.001 us; speedup 1.0000x reference)
//
#include <hip/hip_runtime.h>
#include <hip/hip_bf16.h>
#include <stdint.h>

// Problem constants (fixed by setup_inputs)
#define BATCH    8
#define NTOKB    4096                 // tokens per batch
#define NTOK     (BATCH * NTOKB)     // 32768
#define DIN      512
#define DD       512                 // TOKEN_DIM * NUM_HEADS
#define TD       256                 // TOKEN_DIM
#define SCALE    0.0625f             // 256^-0.5
#define XP       520                 // full-K LDS row stride (ushorts, 1040 B):
                                     // 1040%128=16 -> frag start bank 4*(m+quad+4c)%32,
                                     // 8 groups x 8 lanes tile all 32 banks = optimal

typedef unsigned short ushortT;
typedef __attribute__((ext_vector_type(8))) short  short8;   // 8 bf16 = 4 VGPR
typedef __attribute__((ext_vector_type(4))) float  f32x4;

__device__ __forceinline__ float bf_lo(uint32_t u) { return __uint_as_float(u << 16); }
__device__ __forceinline__ float bf_hi(uint32_t u) { return __uint_as_float(u & 0xffff0000u); }
// round-to-nearest-even f32 -> bf16
__device__ __forceinline__ ushortT f2bf(float f) {
    uint32_t u = __float_as_uint(f);
    return (ushortT)((u + 0x7fffu + ((u >> 16) & 1u)) >> 16);
}

// One K=32 chunk: 4 ds_read_b128 A-frags + 16 MFMA + (optional) 4 global
// 16B W-frag prefetches for chunk pc into the SAME reg buffer (consumed
// this chunk, refilled for pc). No barriers anywhere in the K-loop.
template<int CHSTR>
__device__ __forceinline__ void k_step(
    const ushortT* xbase, const ushortT* __restrict__ wbase,
    int c, int pc, bool preload, short8* breg, f32x4 (&acc)[4][4])
{
    short8 af[4];
    #pragma unroll
    for (int tr = 0; tr < 4; ++tr)
        af[tr] = *reinterpret_cast<const short8*>(xbase + tr * 16 * XP + c * 32);
    #pragma unroll
    for (int tc = 0; tc < 4; ++tc) {
        #pragma unroll
        for (int tr = 0; tr < 4; ++tr)
            acc[tr][tc] = __builtin_amdgcn_mfma_f32_16x16x32_bf16(
                af[tr], breg[tc], acc[tr][tc], 0, 0, 0);
        if (preload)
            breg[tc] = *reinterpret_cast<const short8*>(
                wbase + (size_t)pc * CHSTR + tc * 512);
    }
}

// ---------------------------------------------------------------------------
// K0: pack weights fp32 -> bf16 chunk-tiled B^T form [chunk][n][k32] (dense,
// linear — consumers read global directly into regs, no LDS, no swizzle).
// blocks 0..15: Wq, 16..31: Wk (n=512), 32..47: Wr (n=256).
// ---------------------------------------------------------------------------
__global__ __launch_bounds__(256) void packw_kernel(
    const float* __restrict__ Wq, const float* __restrict__ Wk,
    const float* __restrict__ Wr, ushortT* __restrict__ W16)
{
    const int blk = blockIdx.x;
    if (blk < 32) {
        const int mat = blk >> 4, c = blk & 15;
        const float* S = mat ? Wk : Wq;
        ushortT* D = W16 + (size_t)mat * (512 * 512) + (size_t)c * 16384;
        for (int i = threadIdx.x; i < 16384; i += 256) {
            int n = i & 511, kk = i >> 9;             // consecutive n -> coalesced read
            D[n * 32 + kk] = f2bf(S[(size_t)(c * 32 + kk) * 512 + n]);
        }
    } else {
        const int c = blk - 32;
        ushortT* D = W16 + (size_t)2 * (512 * 512) + (size_t)c * 8192;
        for (int i = threadIdx.x; i < 8192; i += 256) {
            int n = i & 255, kk = i >> 8;
            D[n * 32 + kk] = f2bf(Wr[(size_t)(c * 32 + kk) * 256 + n]);
        }
    }
}

// ---------------------------------------------------------------------------
// K6: MFMA GEMM + FUSED l2norm + alpha: qn/kn = l2norm(x@W + bias) in bf16;
// alpha_raw[t] = SCALE * dot(qn_fp32, w_alpha) (mat==0 only).
// Block = 512 thr (8 waves): 64 tokens x ALL 512 cols (full rows -> fusable).
// W has ZERO intra-block reuse (wave w owns cols w*64..+64, one lane per
// element) -> stream W global->reg from L2 (1.25MB resident), dbuf bA/bB.
// x IS reused by all 8 waves -> full-K x tile (64x512 bf16, 66.5KB) staged
// once in prologue. K-loop is BARRIER-FREE: no vmcnt(0)/lgkmcnt(0) drains.
// LDS 71KB -> 2 blocks/CU; launch_bounds(512,4) caps VGPR 128 (acc64+b32+af16).
// ---------------------------------------------------------------------------
__global__ __launch_bounds__(512, 4) void gemm_qk_kernel(
    const float* __restrict__ x, const ushortT* __restrict__ W16,
    const float* __restrict__ bq, const float* __restrict__ bk,
    const float* __restrict__ w_alpha,
    ushortT* __restrict__ qn, ushortT* __restrict__ kn,
    float* __restrict__ alpha_raw)
{
    __shared__ __align__(16) ushortT xs[64 * XP];    // x tile, full K  66.5 KB
    __shared__ float rowsq[8][64];
    __shared__ float alphap[8][64];
    __shared__ float rnorm_s[64];

    const int tid = threadIdx.x;
    const int mat = blockIdx.y;
    const size_t tok0 = (size_t)blockIdx.x * 64;
    const ushortT* Wb = W16 + (size_t)mat * (512 * 512);
    const float* bias = mat ? bk : bq;
    ushortT* dst = mat ? kn : qn;

    const int lane = tid & 63, w = tid >> 6;    // wave w -> cols [w*64, w*64+64)
    const int m = lane & 15, quad = lane >> 4;

    // per-thread W fragment base: row w*64+m, k-slot quad; frag(c,tc) = +c*16384+tc*512
    const ushortT* wbase = Wb + (w * 64 + m) * 32 + quad * 8;
    short8 bA[4], bB[4];
    #pragma unroll
    for (int tc = 0; tc < 4; ++tc)
        bA[tc] = *reinterpret_cast<const short8*>(wbase + tc * 512);
    #pragma unroll
    for (int tc = 0; tc < 4; ++tc)
        bB[tc] = *reinterpret_cast<const short8*>(wbase + 16384 + tc * 512);

    // ---- prologue: stage FULL x tile (64 tok x 512 k) fp32 -> bf16
    {
        const int xtok = tid >> 3;                 // 0..63
        const int xk4  = (tid & 7) * 4;            // 0..28
        const float* xsrc = x + (tok0 + xtok) * DIN;
        #pragma unroll 4
        for (int c = 0; c < 16; ++c) {
            float4 v = *reinterpret_cast<const float4*>(xsrc + c * 32 + xk4);
            ushort4 b4;
            b4.x = f2bf(v.x); b4.y = f2bf(v.y); b4.z = f2bf(v.z); b4.w = f2bf(v.w);
            *reinterpret_cast<ushort4*>(&xs[xtok * XP + c * 32 + xk4]) = b4;
        }
    }

    f32x4 acc[4][4];
    #pragma unroll
    for (int tr = 0; tr < 4; ++tr)
        #pragma unroll
        for (int tc = 0; tc < 4; ++tc) acc[tr][tc] = (f32x4){0.f, 0.f, 0.f, 0.f};

    __syncthreads();   // x tile visible; ONLY barrier before epilogue

    const ushortT* xbase = xs + m * XP + quad * 8;
    for (int cc = 0; cc < 14; cc += 2) {
        k_step<16384>(xbase, wbase, cc,     cc + 2, true,  bA, acc);
        k_step<16384>(xbase, wbase, cc + 1, cc + 3, true,  bB, acc);
    }
    k_step<16384>(xbase, wbase, 14, 0, false, bA, acc);
    k_step<16384>(xbase, wbase, 15, 0, false, bB, acc);

    // ---- fused epilogue: bias, row ssq + alpha partials, normalize, store
    float biasv[4], wa[4];
    #pragma unroll
    for (int tc = 0; tc < 4; ++tc) {
        biasv[tc] = bias[w * 64 + tc * 16 + m];
        wa[tc] = (mat == 0) ? w_alpha[w * 64 + tc * 16 + m] : 0.f;
    }
    #pragma unroll
    for (int tr = 0; tr < 4; ++tr)
        #pragma unroll
        for (int tc = 0; tc < 4; ++tc)
            #pragma unroll
            for (int reg = 0; reg < 4; ++reg)
                acc[tr][tc][reg] += biasv[tc];

    #pragma unroll
    for (int tr = 0; tr < 4; ++tr) {
        #pragma unroll
        for (int reg = 0; reg < 4; ++reg) {
            float s = 0.f, a = 0.f;
            #pragma unroll
            for (int tc = 0; tc < 4; ++tc) {
                float v = acc[tr][tc][reg];
                s = fmaf(v, v, s);
                a = fmaf(v, wa[tc], a);
            }
            // reduce over the 16 m-lanes of this quad
            #pragma unroll
            for (int off = 1; off < 16; off <<= 1) {
                s += __shfl_xor(s, off);
                a += __shfl_xor(a, off);
            }
            if (m == 0) {
                rowsq[w][tr * 16 + quad * 4 + reg] = s;
                alphap[w][tr * 16 + quad * 4 + reg] = a;
            }
        }
    }
    __syncthreads();
    if (tid < 64) {
        float ss = 0.f, aa = 0.f;
        #pragma unroll
        for (int w2 = 0; w2 < 8; ++w2) { ss += rowsq[w2][tid]; aa += alphap[w2][tid]; }
        float rn = 1.0f / fmaxf(sqrtf(ss), 1e-12f);
        rnorm_s[tid] = rn;
        if (mat == 0) alpha_raw[tok0 + tid] = SCALE * aa * rn;
    }
    __syncthreads();
    #pragma unroll
    for (int tr = 0; tr < 4; ++tr) {
        #pragma unroll
        for (int reg = 0; reg < 4; ++reg) {
            float rn = rnorm_s[tr * 16 + quad * 4 + reg];
            size_t row = tok0 + tr * 16 + quad * 4 + reg;
            ushortT* rp = dst + row * DD + w * 64 + m;
            #pragma unroll
            for (int tc = 0; tc < 4; ++tc)
                rp[tc * 16] = f2bf(acc[tr][tc][reg] * rn);
        }
    }
}

// ---------------------------------------------------------------------------
// K2: per-batch inverse L2 norm of a [4096] vector
// ---------------------------------------------------------------------------
__global__ __launch_bounds__(256) void norm_kernel(const float* __restrict__ in,
                                                   float* __restrict__ inv_out)
{
    int b = blockIdx.x;
    __shared__ float red[256];
    float s = 0.f;
    for (int i = threadIdx.x; i < NTOKB; i += 256) {
        float v = in[b * NTOKB + i];
        s = fmaf(v, v, s);
    }
    red[threadIdx.x] = s;
    __syncthreads();
    for (int off = 128; off > 0; off >>= 1) {
        if (threadIdx.x < off) red[threadIdx.x] += red[threadIdx.x + off];
        __syncthreads();
    }
    if (threadIdx.x == 0) inv_out[b] = 1.0f / fmaxf(sqrtf(red[0]), 1e-12f);
}

// ---------------------------------------------------------------------------
// K3: dst[b,d] += sum_i raw[b,i]*inv[b] * M[b,i,d]   (fp32 atomics; dst pre-zeroed)
// ---------------------------------------------------------------------------
__global__ __launch_bounds__(256) void wsum_kernel(const ushortT* __restrict__ M,
                                                   const float* __restrict__ raw,
                                                   const float* __restrict__ invp,
                                                   float* __restrict__ dst)
{
    const int blk = blockIdx.x, tid = threadIdx.x;
    const int b = blk >> 5;
    const int i0 = (blk & 31) * 128;
    __shared__ float wr[128];
    if (tid < 128) wr[tid] = raw[(size_t)b * NTOKB + i0 + tid];
    __syncthreads();
    const uint32_t* M32 = reinterpret_cast<const uint32_t*>(M);
    size_t base = ((size_t)b * NTOKB + i0) * 256 + tid;
    float a0 = 0.f, a1 = 0.f;
    for (int ii = 0; ii < 128; ++ii) {
        uint32_t v = M32[base + (size_t)ii * 256];
        float wv = wr[ii];
        a0 = fmaf(wv, bf_lo(v), a0);
        a1 = fmaf(wv, bf_hi(v), a1);
    }
    float iv = invp[b];
    atomicAdd(&dst[b * DD + 2 * tid],     a0 * iv);
    atomicAdd(&dst[b * DD + 2 * tid + 1], a1 * iv);
}

// ---------------------------------------------------------------------------
// K4: per-batch softmax over 512; optional premultiplier; optional wb2 output.
// ---------------------------------------------------------------------------
__global__ __launch_bounds__(256) void softmax_kernel(const float* __restrict__ in,
                                                      const float* __restrict__ mul,
                                                      const float* __restrict__ wbeta,
                                                      float* __restrict__ out,
                                                      float* __restrict__ wb2)
{
    int b = blockIdx.x, tid = threadIdx.x;
    __shared__ float red[256];
    float v0 = in[b * DD + tid], v1 = in[b * DD + 256 + tid];
    if (mul) { v0 *= mul[b * DD + tid]; v1 *= mul[b * DD + 256 + tid]; }
    red[tid] = fmaxf(v0, v1);
    __syncthreads();
    for (int off = 128; off > 0; off >>= 1) {
        if (tid < off) red[tid] = fmaxf(red[tid], red[tid + off]);
        __syncthreads();
    }
    float m = red[0];
    __syncthreads();
    float e0 = expf(v0 - m), e1 = expf(v1 - m);
    red[tid] = e0 + e1;
    __syncthreads();
    for (int off = 128; off > 0; off >>= 1) {
        if (tid < off) red[tid] += red[tid + off];
        __syncthreads();
    }
    float rs = 1.0f / red[0];
    float o0 = e0 * rs, o1 = e1 * rs;
    out[b * DD + tid] = o0;
    out[b * DD + 256 + tid] = o1;
    if (wb2) {
        wb2[b * DD + tid]       = o0 * wbeta[tid];
        wb2[b * DD + 256 + tid] = o1 * wbeta[256 + tid];
    }
}

// ---------------------------------------------------------------------------
// K5: beta_raw[tok] = SCALE * dot(kn[tok,:], wb2[b,:])  — one wave per token
// ---------------------------------------------------------------------------
__global__ __launch_bounds__(256) void beta_kernel(const ushortT* __restrict__ kn,
                                                   const float* __restrict__ wb2,
                                                   float* __restrict__ beta_raw)
{
    int wave = threadIdx.x >> 6, lane = threadIdx.x & 63;
    size_t tok = (size_t)blockIdx.x * 4 + wave;
    int b = (int)(tok >> 12);
    uint4 kv = *reinterpret_cast<const uint4*>(kn + tok * DD + lane * 8);
    float4 wv0 = *reinterpret_cast<const float4*>(wb2 + b * DD + lane * 8);
    float4 wv1 = *reinterpret_cast<const float4*>(wb2 + b * DD + lane * 8 + 4);
    float s = bf_lo(kv.x) * wv0.x + bf_hi(kv.x) * wv0.y
            + bf_lo(kv.y) * wv0.z + bf_hi(kv.y) * wv0.w
            + bf_lo(kv.z) * wv1.x + bf_hi(kv.z) * wv1.y
            + bf_lo(kv.w) * wv1.z + bf_hi(kv.w) * wv1.w;
    #pragma unroll
    for (int off = 32; off > 0; off >>= 1) s += __shfl_xor(s, off);
    if (lane == 0) beta_raw[tok] = SCALE * s;
}

// ---------------------------------------------------------------------------
// K8: out = (g_k*kn + qn) @ Wr + br via MFMA. Output fp32.
// Block = 256 thr (4 waves): 64 tokens x 256 cols. Same restructure as K6:
// full-K kvi tile (g_k*kn+qn, bf16, 66.5KB) staged in prologue with 1-ahead
// global prefetch; Wr streamed global->reg (128MB L2 total); K-loop
// barrier-free. NOTE: kn ALIASES d_out — ALL global kn reads complete in the
// prologue (before any epilogue store); blocks own disjoint token ranges.
// ---------------------------------------------------------------------------
__global__ __launch_bounds__(256) void out_mfma_kernel(
    const ushortT* __restrict__ qn, const ushortT* __restrict__ kn,
    const float* __restrict__ g_k, const ushortT* __restrict__ WrT,
    const float* __restrict__ br, float* __restrict__ out)
{
    __shared__ __align__(16) ushortT kvs[64 * XP];   // kvi tile, full K 66.5 KB
    __shared__ float gks[512];

    const int tid = threadIdx.x;
    const size_t tok0 = (size_t)blockIdx.x * 64;
    const int b = (int)(tok0 >> 12);

    gks[tid] = g_k[b * DD + tid];
    gks[256 + tid] = g_k[b * DD + 256 + tid];

    const int lane = tid & 63, w = tid >> 6;    // wave w -> cols [w*64, w*64+64)
    const int m = lane & 15, quad = lane >> 4;

    // W fragment base + prefetch chunks 0,1 (independent of LDS)
    const ushortT* wbase = WrT + (w * 64 + m) * 32 + quad * 8;
    short8 bA[4], bB[4];
    #pragma unroll
    for (int tc = 0; tc < 4; ++tc)
        bA[tc] = *reinterpret_cast<const short8*>(wbase + tc * 512);
    #pragma unroll
    for (int tc = 0; tc < 4; ++tc)
        bB[tc] = *reinterpret_cast<const short8*>(wbase + 8192 + tc * 512);

    const int st  = tid >> 2;           // token 0..63
    const int skg = (tid & 3) * 8;      // k offset 0, 8, 16, 24
    const ushortT* qrow = qn + (tok0 + st) * DD + skg;
    const ushortT* krow = kn + (tok0 + st) * DD + skg;

    uint4 qvA = *reinterpret_cast<const uint4*>(qrow);
    uint4 kvA = *reinterpret_cast<const uint4*>(krow);
    __syncthreads();   // gks visible

    // ---- prologue: pack full kvi tile with 1-chunk-ahead global prefetch
    for (int c = 0; c < 16; ++c) {
        uint4 qvB, kvB;
        if (c + 1 < 16) {
            qvB = *reinterpret_cast<const uint4*>(qrow + (c + 1) * 32);
            kvB = *reinterpret_cast<const uint4*>(krow + (c + 1) * 32);
        }
        const float* g = &gks[c * 32 + skg];
        ushortT o[8];
        o[0] = f2bf(fmaf(g[0], bf_lo(kvA.x), bf_lo(qvA.x)));
        o[1] = f2bf(fmaf(g[1], bf_hi(kvA.x), bf_hi(qvA.x)));
        o[2] = f2bf(fmaf(g[2], bf_lo(kvA.y), bf_lo(qvA.y)));
        o[3] = f2bf(fmaf(g[3], bf_hi(kvA.y), bf_hi(qvA.y)));
        o[4] = f2bf(fmaf(g[4], bf_lo(kvA.z), bf_lo(qvA.z)));
        o[5] = f2bf(fmaf(g[5], bf_hi(kvA.z), bf_hi(qvA.z)));
        o[6] = f2bf(fmaf(g[6], bf_lo(kvA.w), bf_lo(qvA.w)));
        o[7] = f2bf(fmaf(g[7], bf_hi(kvA.w), bf_hi(qvA.w)));
        uint2* lp = reinterpret_cast<uint2*>(&kvs[st * XP + c * 32 + skg]);
        lp[0] = make_uint2(((uint32_t)o[1] << 16) | o[0], ((uint32_t)o[3] << 16) | o[2]);
        lp[1] = make_uint2(((uint32_t)o[5] << 16) | o[4], ((uint32_t)o[7] << 16) | o[6]);
        qvA = qvB; kvA = kvB;
    }

    f32x4 acc[4][4];
    #pragma unroll
    for (int tr = 0; tr < 4; ++tr)
        #pragma unroll
        for (int tc = 0; tc < 4; ++tc) acc[tr][tc] = (f32x4){0.f, 0.f, 0.f, 0.f};

    __syncthreads();   // kvi tile visible; K-loop below is barrier-free

    const ushortT* xbase = kvs + m * XP + quad * 8;
    for (int cc = 0; cc < 14; cc += 2) {
        k_step<8192>(xbase, wbase, cc,     cc + 2, true,  bA, acc);
        k_step<8192>(xbase, wbase, cc + 1, cc + 3, true,  bB, acc);
    }
    k_step<8192>(xbase, wbase, 14, 0, false, bA, acc);
    k_step<8192>(xbase, wbase, 15, 0, false, bB, acc);

    // ---- epilogue: + br, store fp32 (overwrites kn alias range for own tokens)
    float brv[4];
    #pragma unroll
    for (int tc = 0; tc < 4; ++tc) brv[tc] = br[w * 64 + tc * 16 + m];
    #pragma unroll
    for (int tr = 0; tr < 4; ++tr) {
        #pragma unroll
        for (int reg = 0; reg < 4; ++reg) {
            size_t row = tok0 + tr * 16 + quad * 4 + reg;
            float* rp = out + row * TD + w * 64 + m;
            #pragma unroll
            for (int tc = 0; tc < 4; ++tc)
                rp[tc * 16] = acc[tr][tc][reg] + brv[tc];
        }
    }
}

// ---------------------------------------------------------------------------
extern "C" void kernel_launch(void* const* d_in, const int* in_sizes, int n_in,
                              void* d_out, int out_size, void* d_ws, size_t ws_size,
                              hipStream_t stream)
{
    const float* x       = (const float*)d_in[0];
    const float* Wq      = (const float*)d_in[1];
    const float* bq      = (const float*)d_in[2];
    const float* Wk      = (const float*)d_in[3];
    const float* bk      = (const float*)d_in[4];
    const float* Wr      = (const float*)d_in[5];
    const float* br      = (const float*)d_in[6];
    const float* w_alpha = (const float*)d_in[7];
    const float* w_beta  = (const float*)d_in[8];
    float* out = (float*)d_out;

    // kn ALIASES d_out (byte-identical token ranges); total ws ~33.7 MB.
    ushortT* kn = (ushortT*)d_out;

    char* ws = (char*)d_ws;
    ushortT* qn = (ushortT*)ws;        ws += (size_t)NTOK * DD * sizeof(ushortT);      // 32 MiB
    ushortT* W16 = (ushortT*)ws;       ws += (size_t)2 * 512 * 512 * sizeof(ushortT)
                                           + (size_t)512 * 256 * sizeof(ushortT);       // 1.25 MiB (Wq,Wk,Wr)
    float* alpha_raw = (float*)ws;     ws += (size_t)NTOK * sizeof(float);
    float* beta_raw  = (float*)ws;     ws += (size_t)NTOK * sizeof(float);
    float* gq_raw = (float*)ws;        ws += (size_t)BATCH * DD * sizeof(float);
    float* h_raw  = (float*)ws;        ws += (size_t)BATCH * DD * sizeof(float);  // contiguous w/ gq_raw
    float* g_q    = (float*)ws;        ws += (size_t)BATCH * DD * sizeof(float);
    float* wb2    = (float*)ws;        ws += (size_t)BATCH * DD * sizeof(float);
    float* g_k    = (float*)ws;        ws += (size_t)BATCH * DD * sizeof(float);
    float* inv_a  = (float*)ws;        ws += 64;
    float* inv_b  = (float*)ws;        ws += 64;
    ushortT* WrT = W16 + (size_t)2 * 512 * 512;

    hipMemsetAsync(gq_raw, 0, 2 * BATCH * DD * sizeof(float), stream);

    packw_kernel<<<48, 256, 0, stream>>>(Wq, Wk, Wr, W16);
    gemm_qk_kernel<<<dim3(NTOK / 64, 2), 512, 0, stream>>>(x, W16, bq, bk, w_alpha, qn, kn, alpha_raw);
    norm_kernel<<<BATCH, 256, 0, stream>>>(alpha_raw, inv_a);
    wsum_kernel<<<256, 256, 0, stream>>>(qn, alpha_raw, inv_a, gq_raw);
    softmax_kernel<<<BATCH, 256, 0, stream>>>(gq_raw, nullptr, w_beta, g_q, wb2);
    beta_kernel<<<NTOK / 4, 256, 0, stream>>>(kn, wb2, beta_raw);
    norm_kernel<<<BATCH, 256, 0, stream>>>(beta_raw, inv_b);
    wsum_kernel<<<256, 256, 0, stream>>>(kn, beta_raw, inv_b, h_raw);
    softmax_kernel<<<BATCH, 256, 0, stream>>>(h_raw, g_q, nullptr, g_k, nullptr);
    out_mfma_kernel<<<NTOK / 64, 256, 0, stream>>>(qn, kn, g_k, WrT, br, out);
}